// Round 4
// baseline (390.950 us; speedup 1.0000x reference)
//
#include <hip/hip_runtime.h>
#include <hip/hip_bf16.h>

typedef __attribute__((ext_vector_type(8))) short short8;
typedef __attribute__((ext_vector_type(4))) short short4v;
typedef __attribute__((ext_vector_type(4))) float f32x4;

#define DEVI static __device__ __forceinline__

constexpr int T_SEQ = 256, DK = 128, DV = 128, CH = 64, NCH = 4;
constexpr int NPAIR = 512;
constexpr size_t OUT_ELEMS = (size_t)NPAIR * T_SEQ * DV;

// ---- LDS layout (bytes) ----
constexpr int OFF_SB   = 0;       // S^T [dv=128][dk bf16, 256B rows] swz16
constexpr int OFF_KC   = 32768;   // kc  [j=64][dk, 256B rows] swz16
constexpr int OFF_KRQS = 49152;   // kr then qs [i=64][dk, 256B rows] swz16
constexpr int OFF_XT   = 65536;   // X^T [dv=128][64 cols, 256B rows] swz16 (vbT -> X -> vnT)
constexpr int OFF_KCT  = 98304;   // kc^T [dk=128][j=64, 128B rows] swz8
constexpr int OFF_PA   = 114688;  // P    [64][160B rows] swz8  (also McBuf in tail)
constexpr int OFF_PTA  = 124928;  // P^T
constexpr int OFF_PB   = 135168;  // ping-pong P
constexpr int OFF_PTB  = 145408;  // ping-pong P^T
constexpr int OFF_EPOS = 155648;  // 64 f32
constexpr int OFF_ENEG = 155904;  // 64 f32
constexpr int OFF_GC   = 156160;  // 256 f32
constexpr int OFF_BETA = 157184;  // 256 f32
constexpr int OFF_WS   = 158208;  // 8 f32
constexpr int LDS_BYTES = 158240;

DEVI unsigned short f2bf(float f) {
  union { float f; unsigned u; } a; a.f = f;
  unsigned r = a.u + 0x7fffu + ((a.u >> 16) & 1u);
  return (unsigned short)(r >> 16);
}
DEVI float bf2f(unsigned short h) {
  union { unsigned u; float f; } a; a.u = ((unsigned)h) << 16;
  return a.f;
}
DEVI f32x4 mfma(short8 a, short8 b, f32x4 c) {
  return __builtin_amdgcn_mfma_f32_16x16x32_bf16(a, b, c, 0, 0, 0);
}
// stride-256 buffers, 16-slot swizzle
DEVI short8 ld16(const char* s, int row, int kb) {
  return *(const short8*)(s + row * 256 + (((row & 15) << 4) ^ kb));
}
DEVI void st4_16(char* s, int row, int col0, short4v p) {
  *(short4v*)(s + row * 256 + (((row & 15) << 4) ^ (col0 * 2))) = p;
}
// generic-stride buffers, 8-slot swizzle
DEVI short8 ld8(const char* s, int stride, int row, int kb) {
  return *(const short8*)(s + row * stride + (((row & 7) << 4) ^ kb));
}
DEVI void st4_8(char* s, int stride, int row, int col0, short4v p) {
  *(short4v*)(s + row * stride + (((row & 7) << 4) ^ (col0 * 2))) = p;
}
DEVI short4v pack4(f32x4 v) {
  short4v p;
  p[0] = (short)f2bf(v[0]); p[1] = (short)f2bf(v[1]);
  p[2] = (short)f2bf(v[2]); p[3] = (short)f2bf(v[3]);
  return p;
}

__global__ __launch_bounds__(512, 1)
void cra_fwd(const float* __restrict__ qg_, const float* __restrict__ kg_,
             const float* __restrict__ vg_, const float* __restrict__ gg_,
             const float* __restrict__ bg_, const float* __restrict__ s0g_,
             float* __restrict__ outg_)
{
  extern __shared__ char sm[];
  const int tid = threadIdx.x;
  const int lane = tid & 63, w = tid >> 6;
  const int l15 = lane & 15, l4 = lane >> 4;
  const int kb0 = l4 * 16;               // fragment k byte offset within 64B k-slot
  const int pair = blockIdx.x;

  const size_t rowbase = (size_t)pair * T_SEQ;
  const float* qg = qg_ + rowbase * DK;
  const float* kg = kg_ + rowbase * DK;
  const float* vg = vg_ + rowbase * DV;
  float* outg = outg_ + rowbase * DV;
  float* soutg = outg_ + OUT_ELEMS + (size_t)pair * DK * DV;

  float* gc    = (float*)(sm + OFF_GC);
  float* bet   = (float*)(sm + OFF_BETA);
  float* eposA = (float*)(sm + OFF_EPOS);
  float* enegA = (float*)(sm + OFF_ENEG);
  float* wsum  = (float*)(sm + OFF_WS);

  // ---- S init (C-layout: m=dk rows, n=dv cols; wave w owns dk block w*16)
  f32x4 Sacc[8];
  {
    const float* Sp = s0g_ + (size_t)pair * DK * DV;
    const int dk0 = w * 16 + l4 * 4;
#pragma unroll
    for (int tn = 0; tn < 8; ++tn) {
      const int dv = tn * 16 + l15;
#pragma unroll
      for (int rr = 0; rr < 4; ++rr)
        Sacc[tn][rr] = Sp[(size_t)(dk0 + rr) * DV + dv];
    }
  }

  // ---- cumsum of g; stage beta; issue chunk-0 k/v loads
  const int r = tid >> 3, u = tid & 7;
  float4 kv[4], vv[4];
  {
    const float4* kp = (const float4*)(kg + (size_t)r * DK);
    const float4* vp = (const float4*)(vg + (size_t)r * DV);
#pragma unroll
    for (int j = 0; j < 4; ++j) { kv[j] = kp[u + 8 * j]; vv[j] = vp[u + 8 * j]; }
  }
  if (tid < 256) {
    float x = gg_[rowbase + tid];
    bet[tid] = bg_[rowbase + tid];
#pragma unroll
    for (int d = 1; d < 64; d <<= 1) {
      float y = __shfl_up(x, d, 64);
      if (lane >= d) x += y;
    }
    if (lane == 63) wsum[w] = x;
    gc[tid] = x;
  }
  __syncthreads();
  if (tid < 256) {
    float pre = 0.f;
    for (int j = 0; j < w; ++j) pre += wsum[j];
    gc[tid] += pre;
  }
  __syncthreads();

  const f32x4 zero = {0.f, 0.f, 0.f, 0.f};
  const int tmB = (w >> 1) * 16;

#pragma unroll 1
  for (int c = 0; c < NCH; ++c) {
    const int t0 = c * CH;
    // P_top: per-chunk scales (same phase as previous chunk's tail)
    if (tid < 64) {
      const float base = (c == 0) ? 0.f : gc[t0 - 1];
      const float lc = gc[t0 + tid] - base;
      eposA[tid] = __expf(lc);
      enegA[tid] = __expf(-lc);
    }
    __syncthreads();  // S_a

    // ---- P_stage: kr, kc (st4), kcT, vbT (2B col writes), S->SB dump
    {
      const float be = bet[t0 + r], ep = eposA[r], en = enegA[r];
      const float krs = be * ep;
#pragma unroll
      for (int j = 0; j < 4; ++j) {
        const int col0 = 4 * (u + 8 * j);
        const float kf[4] = {kv[j].x, kv[j].y, kv[j].z, kv[j].w};
        const float vf[4] = {vv[j].x, vv[j].y, vv[j].z, vv[j].w};
        short4v pr, pc;
#pragma unroll
        for (int e = 0; e < 4; ++e) {
          pr[e] = (short)f2bf(kf[e] * krs);
          pc[e] = (short)f2bf(kf[e] * en);
        }
        st4_16(sm + OFF_KRQS, r, col0, pr);
        st4_16(sm + OFF_KC,   r, col0, pc);
#pragma unroll
        for (int e = 0; e < 4; ++e) {
          const int d = col0 + e;
          *(unsigned short*)(sm + OFF_KCT + d * 128 + (((d & 7) << 4) ^ (r * 2))) = f2bf(kf[e] * en);
          *(unsigned short*)(sm + OFF_XT  + d * 256 + (((d & 15) << 4) ^ (r * 2))) = f2bf(vf[e] * be);
        }
      }
      const int dk0 = w * 16 + l4 * 4;
#pragma unroll
      for (int tn = 0; tn < 8; ++tn)
        st4_16(sm + OFF_SB, tn * 16 + l15, dk0, pack4(Sacc[tn]));
    }
    __syncthreads();  // S_b

    // ---- P_big: q loads; P/Pt init (dual-orientation KKT, masked st4); R RMW into XT
    float4 qv[4];
    {
      const float4* qp = (const float4*)(qg + (size_t)(t0 + r) * DK);
#pragma unroll
      for (int j = 0; j < 4; ++j) qv[j] = qp[u + 8 * j];
    }
#pragma unroll
    for (int s = 0; s < 2; ++s) {   // Pt init: C = kr@kc^T = KKT[i][j], st4 -> Pt[j][i]
      const int nt = (w & 1) * 2 + s;
      f32x4 acc = zero;
#pragma unroll
      for (int ks = 0; ks < 4; ++ks)
        acc = mfma(ld16(sm + OFF_KRQS, tmB + l15, ks * 64 + kb0),
                   ld16(sm + OFF_KC,   nt * 16 + l15, ks * 64 + kb0), acc);
      const int jj = nt * 16 + l15, i0 = tmB + l4 * 4;
      short4v p;
#pragma unroll
      for (int rr = 0; rr < 4; ++rr) {
        const int i = i0 + rr;
        p[rr] = (short)f2bf((i > jj) ? -acc[rr] : 0.f);
      }
      st4_8(sm + OFF_PTA, 160, jj, i0, p);
    }
#pragma unroll
    for (int s = 0; s < 2; ++s) {   // P init: C' = kc@kr^T = KKT[i][j] (m=j,n=i), st4 -> P[i][j]
      const int nt = (w & 1) * 2 + s;
      f32x4 acc = zero;
#pragma unroll
      for (int ks = 0; ks < 4; ++ks)
        acc = mfma(ld16(sm + OFF_KC,   tmB + l15, ks * 64 + kb0),
                   ld16(sm + OFF_KRQS, nt * 16 + l15, ks * 64 + kb0), acc);
      const int ii = nt * 16 + l15, j0 = tmB + l4 * 4;
      short4v p;
#pragma unroll
      for (int rr = 0; rr < 4; ++rr) {
        const int j = j0 + rr;
        p[rr] = (short)f2bf((ii > j) ? -acc[rr] : 0.f);
      }
      st4_8(sm + OFF_PA, 160, ii, j0, p);
    }
#pragma unroll
    for (int s = 0; s < 4; ++s) {   // R: Xt -= kr@S   (Xt init'd with beta*v^T)
      const int dvt = (w & 1) * 4 + s;
      f32x4 acc = zero;
#pragma unroll
      for (int ks = 0; ks < 4; ++ks)
        acc = mfma(ld16(sm + OFF_KRQS, tmB + l15, ks * 64 + kb0),
                   ld16(sm + OFF_SB,   dvt * 16 + l15, ks * 64 + kb0), acc);
      const int dv = dvt * 16 + l15, i0 = tmB + l4 * 4;
      char* p = sm + OFF_XT + dv * 256 + (((dv & 15) << 4) ^ (i0 * 2));
      short4v old = *(const short4v*)p, nw;
#pragma unroll
      for (int rr = 0; rr < 4; ++rr)
        nw[rr] = (short)f2bf(bf2f((unsigned short)old[rr]) - acc[rr]);
      *(short4v*)p = nw;
    }

    // ---- doubling on the solution: X <- (I + P^{2^it}) X ; P <- P^2.  Exact in 6 iters.
#pragma unroll
    for (int it = 0; it < 6; ++it) {
      __syncthreads();
      const char* Pc  = (it & 1) ? sm + OFF_PB  : sm + OFF_PA;
      const char* PTc = (it & 1) ? sm + OFF_PTB : sm + OFF_PTA;
      char* Pn  = (it & 1) ? sm + OFF_PA  : sm + OFF_PB;
      char* PTn = (it & 1) ? sm + OFF_PTA : sm + OFF_PTB;

      // X-update: wave owns dv rows [w*16, w*16+16)
      short8 bb[2];
#pragma unroll
      for (int ks = 0; ks < 2; ++ks)
        bb[ks] = ld16(sm + OFF_XT, w * 16 + l15, ks * 64 + kb0);
      f32x4 xa[4];
#pragma unroll
      for (int itile = 0; itile < 4; ++itile) {
        f32x4 acc = zero;
#pragma unroll
        for (int ks = 0; ks < 2; ++ks)
          acc = mfma(ld8(Pc, 160, itile * 16 + l15, ks * 64 + kb0), bb[ks], acc);
        xa[itile] = acc;
      }
      if (it == 0) {  // stage qs = e^{lc} q over kr (kr dead after P_big)
        const float ep = eposA[r];
#pragma unroll
        for (int j = 0; j < 4; ++j) {
          const int col0 = 4 * (u + 8 * j);
          const float qf[4] = {qv[j].x, qv[j].y, qv[j].z, qv[j].w};
          short4v pq;
#pragma unroll
          for (int e = 0; e < 4; ++e) pq[e] = (short)f2bf(qf[e] * ep);
          st4_16(sm + OFF_KRQS, r, col0, pq);
        }
      }
      if (it < 5) {  // P^2 pair into ping-pong buffers (st4-transpose trick, no scatters)
#pragma unroll
        for (int s = 0; s < 2; ++s) {
          const int nt = (w & 1) * 2 + s;
          f32x4 a1 = zero, a2 = zero;
#pragma unroll
          for (int ks = 0; ks < 2; ++ks) {
            a1 = mfma(ld8(Pc,  160, tmB + l15, ks * 64 + kb0),
                      ld8(PTc, 160, nt * 16 + l15, ks * 64 + kb0), a1);  // C = P@P -> st4 gives (P^2)^T
            a2 = mfma(ld8(PTc, 160, tmB + l15, ks * 64 + kb0),
                      ld8(Pc,  160, nt * 16 + l15, ks * 64 + kb0), a2);  // C' = (P^2)^T -> st4 gives P^2
          }
          st4_8(PTn, 160, nt * 16 + l15, tmB + l4 * 4, pack4(a1));
          st4_8(Pn,  160, nt * 16 + l15, tmB + l4 * 4, pack4(a2));
        }
      }
      // RMW X (own rows only -> no cross-wave race)
#pragma unroll
      for (int itile = 0; itile < 4; ++itile) {
        const int row = w * 16 + l15;
        char* p = sm + OFF_XT + row * 256 + (((row & 15) << 4) ^ ((itile * 16 + l4 * 4) * 2));
        short4v old = *(const short4v*)p, nw;
#pragma unroll
        for (int rr = 0; rr < 4; ++rr)
          nw[rr] = (short)f2bf(bf2f((unsigned short)old[rr]) + xa[itile][rr]);
        *(short4v*)p = nw;
      }
    }
    __syncthreads();  // S_d

    // ---- P_tail1: inter = qs@S ; Mc = tril(qs@kc^T,0) -> PA ; S update
    f32x4 outA[4];
#pragma unroll
    for (int s = 0; s < 4; ++s) {
      const int dvt = (w & 1) * 4 + s;
      f32x4 acc = zero;
#pragma unroll
      for (int ks = 0; ks < 4; ++ks)
        acc = mfma(ld16(sm + OFF_KRQS, tmB + l15, ks * 64 + kb0),
                   ld16(sm + OFF_SB,   dvt * 16 + l15, ks * 64 + kb0), acc);
      outA[s] = acc;
    }
#pragma unroll
    for (int s = 0; s < 2; ++s) {   // C' = kc@qs^T (m=j, n=i) -> st4 -> Mc[i][j] masked i>=j
      const int nt = (w & 1) * 2 + s;
      f32x4 acc = zero;
#pragma unroll
      for (int ks = 0; ks < 4; ++ks)
        acc = mfma(ld16(sm + OFF_KC,   tmB + l15, ks * 64 + kb0),
                   ld16(sm + OFF_KRQS, nt * 16 + l15, ks * 64 + kb0), acc);
      const int ii = nt * 16 + l15, j0 = tmB + l4 * 4;
      short4v p;
#pragma unroll
      for (int rr = 0; rr < 4; ++rr) {
        const int j = j0 + rr;
        p[rr] = (short)f2bf((ii >= j) ? acc[rr] : 0.f);
      }
      st4_8(sm + OFF_PA, 160, ii, j0, p);
    }
    {
      const float eG = eposA[CH - 1];
#pragma unroll
      for (int tn = 0; tn < 8; ++tn) {
#pragma unroll
        for (int ks = 0; ks < 2; ++ks)
          Sacc[tn] = mfma(ld8(sm + OFF_KCT, 128, w * 16 + l15, ks * 64 + kb0),
                          ld16(sm + OFF_XT, tn * 16 + l15, ks * 64 + kb0), Sacc[tn]);
#pragma unroll
        for (int rr = 0; rr < 4; ++rr) Sacc[tn][rr] *= eG;
      }
    }
    __syncthreads();  // S_e

    // ---- P_tail2: prefetch next k/v; intra; direct out stores
    if (c + 1 < NCH) {
      const float4* kp = (const float4*)(kg + (size_t)((c + 1) * CH + r) * DK);
      const float4* vp = (const float4*)(vg + (size_t)((c + 1) * CH + r) * DV);
#pragma unroll
      for (int j = 0; j < 4; ++j) { kv[j] = kp[u + 8 * j]; vv[j] = vp[u + 8 * j]; }
    }
#pragma unroll
    for (int s = 0; s < 4; ++s) {
      const int dvt = (w & 1) * 4 + s;
#pragma unroll
      for (int ks = 0; ks < 2; ++ks)
        outA[s] = mfma(ld8(sm + OFF_PA, 160, tmB + l15, ks * 64 + kb0),
                       ld16(sm + OFF_XT, dvt * 16 + l15, ks * 64 + kb0), outA[s]);
      const int dv = dvt * 16 + l15, i0 = tmB + l4 * 4;
#pragma unroll
      for (int rr = 0; rr < 4; ++rr)
        outg[(size_t)(t0 + i0 + rr) * DV + dv] = outA[s][rr];
    }
  }  // chunk loop

  // ---- final state store (direct)
  {
    const int dk0 = w * 16 + l4 * 4;
#pragma unroll
    for (int tn = 0; tn < 8; ++tn) {
      const int dv = tn * 16 + l15;
#pragma unroll
      for (int rr = 0; rr < 4; ++rr)
        soutg[(size_t)(dk0 + rr) * DV + dv] = Sacc[tn][rr];
    }
  }
}

extern "C" void kernel_launch(void* const* d_in, const int* in_sizes, int n_in,
                              void* d_out, int out_size, void* d_ws, size_t ws_size,
                              hipStream_t stream) {
  (void)in_sizes; (void)n_in; (void)out_size; (void)d_ws; (void)ws_size;
  const float* q  = (const float*)d_in[0];
  const float* k  = (const float*)d_in[1];
  const float* v  = (const float*)d_in[2];
  const float* g  = (const float*)d_in[3];
  const float* b  = (const float*)d_in[4];
  const float* s0 = (const float*)d_in[5];
  hipFuncSetAttribute((const void*)cra_fwd,
                      hipFuncAttributeMaxDynamicSharedMemorySize, LDS_BYTES);
  hipLaunchKernelGGL(cra_fwd, dim3(NPAIR), dim3(512), LDS_BYTES, stream,
                     q, k, v, g, b, s0, (float*)d_out);
}